// Round 19
// baseline (131.803 us; speedup 1.0000x reference)
//
#include <hip/hip_runtime.h>
#include <hip/hip_bf16.h>
#include <math.h>

#define BATCH 8192
#define IMG 784   // 28*28
#define KP 800    // fc1 K padded to multiple of 32
#define KP2 416   // fc2 K padded (400 -> 416)

typedef short  bf16x8 __attribute__((ext_vector_type(8)));
typedef float  f32x4  __attribute__((ext_vector_type(4)));
typedef float  f32x2  __attribute__((ext_vector_type(2)));

// ---------------------------------------------------------------------------
// K0: precompute (a) per-class conv0 tables T4[10][784] float4 (3ch+pad),
// (b) parity-folded deconv1 weights WF4 + packed w1p/dw2p/dw0p,
// (c) fc1_w -> bf16 [400][800], (d) fc2 weights -> bf16 [48][416],
// (e) fc3_w -> bf16 [400][32].
// ---------------------------------------------------------------------------
__global__ __launch_bounds__(256) void precompute_kernel(
    const float* __restrict__ w0,    // [3,11,3,3]
    const float* __restrict__ w1,    // [1,3,3,3]
    const float* __restrict__ dw0,   // [11,2,3,3]
    const float* __restrict__ dw1,   // [3,11,3,3]
    const float* __restrict__ dw2,   // [1,3,3,3]
    const float* __restrict__ fc1w,  // [400,784]
    const float* __restrict__ w21,   // [20,400]
    const float* __restrict__ w22,   // [20,400]
    const float* __restrict__ fc3w,  // [392,30]
    float* __restrict__ T4,          // [10,784,4]
    float* __restrict__ WF4,         // 576 floats
    float* __restrict__ w1p,         // [9]*4 floats
    float* __restrict__ dw2p,        // [9]*4 floats
    float* __restrict__ dw0p,        // [2*9*3]*4 = 216 floats
    __hip_bfloat16* __restrict__ wbf,   // [400,800]
    __hip_bfloat16* __restrict__ w2bf,  // [48,416]
    __hip_bfloat16* __restrict__ w3bf)  // [400,32]
{
    const int blk = blockIdx.x, tid = threadIdx.x;
    if (blk < 10) {
        const int t = blk;
        for (int idx = tid; idx < 4 * 784; idx += 256) {
            int o = idx / 784, pix = idx % 784;
            float acc = 0.f;
            if (o < 3) {
                int r = pix / 28, c = pix % 28;
#pragma unroll
                for (int dr = 0; dr < 3; ++dr)
#pragma unroll
                    for (int dc = 0; dc < 3; ++dc) {
                        int rr = r + dr - 1, cc = c + dc - 1;
                        if (rr < 0 || rr > 27 || cc < 0 || cc > 27) continue;
                        int s = rr * 28 + cc;
                        int i = ((4 * (t + 1 - s)) % 11 + 11) % 11;
                        acc += w0[(o * 11 + i) * 9 + dr * 3 + dc];
                    }
            }
            T4[(t * 784 + pix) * 4 + o] = acc;
        }
    } else if (blk == 10) {
        // WF4 flat idx = (((par*3+o)*4+uv)*3+cb)*4+j ; channel = 4*cb+j
        for (int idx = tid; idx < 576; idx += 256) {
            int j = idx & 3;
            int rest = idx >> 2;
            int cb = rest % 3;
            int rest2 = rest / 3;
            int uv = rest2 % 4;
            int rest3 = rest2 / 4;
            int o = rest3 % 3;
            int par = rest3 / 3;
            int ch = cb * 4 + j;
            float acc = 0.f;
            if (ch < 11) {
                int u = uv >> 1, v = uv & 1;
                int pr = par >> 1, pc = par & 1;
                for (int dr = 0; dr < 3; ++dr) {
                    bool rin = (pr == 0) ? (u == 0 ? dr == 0 : dr >= 1)
                                         : (u == 0 ? dr <= 1 : dr == 2);
                    if (!rin) continue;
                    for (int dc = 0; dc < 3; ++dc) {
                        bool cin = (pc == 0) ? (v == 0 ? dc == 0 : dc >= 1)
                                             : (v == 0 ? dc <= 1 : dc == 2);
                        if (cin) acc += dw1[(o * 11 + ch) * 9 + dr * 3 + dc];
                    }
                }
            }
            WF4[idx] = acc;
        }
        // per-tap packed conv1 / deconv2 weights: {w[t], w[9+t], w[18+t], 0}
        if (tid < 9) {
            w1p[tid * 4 + 0] = w1[tid];
            w1p[tid * 4 + 1] = w1[9 + tid];
            w1p[tid * 4 + 2] = w1[18 + tid];
            w1p[tid * 4 + 3] = 0.f;
        } else if (tid < 18) {
            int t = tid - 9;
            dw2p[t * 4 + 0] = dw2[t];
            dw2p[t * 4 + 1] = dw2[9 + t];
            dw2p[t * 4 + 2] = dw2[18 + t];
            dw2p[t * 4 + 3] = 0.f;
        }
        // deconv0 weights channel-minor: dw0p[(i*9+tap)*12 + ch]
        if (tid >= 32 && tid < 248) {
            int idx = tid - 32;            // 0..215
            int j  = idx & 3;
            int cb = (idx >> 2) % 3;
            int t2 = (idx >> 2) / 3;       // i*9 + tap, 0..17
            int i  = t2 / 9, tap = t2 % 9;
            int ch = cb * 4 + j;
            dw0p[t2 * 12 + cb * 4 + j] =
                (ch < 11) ? dw0[(ch * 2 + i) * 9 + tap] : 0.f;
        }
    } else if (blk < 51) {
        // fc1_w fp32 [400,784] -> bf16 [400,800] (cols 784..799 zero)
        const int base = (blk - 11) * 8000;
        for (int i = tid; i < 8000; i += 256) {
            int flat = base + i;
            int n = flat / KP, k = flat % KP;
            float v = (k < 784) ? fc1w[n * 784 + k] : 0.f;
            wbf[flat] = __float2bfloat16(v);
        }
    } else if (blk < 59) {
        // fc2 weights -> bf16 [48,416]: rows 0-19 w21, 20-39 w22, 40-47 zero
        const int base = (blk - 51) * 2496;
        for (int i = tid; i < 2496; i += 256) {
            int flat = base + i;
            int j = flat / KP2, k = flat % KP2;
            float v = 0.f;
            if (k < 400) {
                if (j < 20)      v = w21[j * 400 + k];
                else if (j < 40) v = w22[(j - 20) * 400 + k];
            }
            w2bf[flat] = __float2bfloat16(v);
        }
    } else {
        // fc3_w -> bf16 [400][32]
        for (int i = tid; i < 400 * 32; i += 256) {
            int n = i >> 5, k = i & 31;
            float v = (n < 392 && k < 30) ? fc3w[n * 30 + k] : 0.f;
            w3bf[i] = __float2bfloat16(v);
        }
    }
}

// ---------------------------------------------------------------------------
// K1: encoder — coalesced-x inverse scatter + sparse-x conv0 + conv1,
// vertical 2-pixel pairing, float4 T table. LDS 19.6KB -> (256,8) occupancy.
// ---------------------------------------------------------------------------
__global__ __launch_bounds__(256, 8) void encoder_kernel(
    const float* __restrict__ x, const int* __restrict__ cls,
    const float* __restrict__ w0,    // [3,11,3,3]
    const float* __restrict__ w1p,   // [9] float4 packed
    const float* __restrict__ T4,    // [10,784] float4
    __hip_bfloat16* __restrict__ h_bf)  // [B,800]
{
    __shared__ float  xs[30 * 30];      // scattered x image, zero border
    __shared__ float4 hs0[30 * 30];     // conv0 out (3ch + pad), zero border
    __shared__ float4 wt2[99];          // [cls 0..10][tap 0..8] pre-permuted

    const int b = blockIdx.x, tid = threadIdx.x;
    const int myc = cls[b];

    for (int i = tid; i < 116; i += 256) {
        int r, c;
        if (i < 30)      { r = 0;  c = i; }
        else if (i < 60) { r = 29; c = i - 30; }
        else if (i < 88) { r = 1 + (i - 60); c = 0; }
        else             { r = 1 + (i - 88); c = 29; }
        xs[r * 30 + c] = 0.f;
        hs0[r * 30 + c] = make_float4(0.f, 0.f, 0.f, 0.f);
    }
    // wt2[cls*9+tap] = w0[:, (cls + kk(tap)) % 11, tap]
    for (int i = tid; i < 99; i += 256) {
        int cl = i / 9, tap = i % 9;
        int kk = (9 * (tap / 3) + 7 * (tap % 3)) % 11;
        int ch = cl + kk;
        if (ch >= 11) ch -= 11;
        wt2[i] = make_float4(w0[ch * 9 + tap], w0[(11 + ch) * 9 + tap],
                             w0[(22 + ch) * 9 + tap], 0.f);
    }
    // inverse scatter: x element p lives at spatial s = (11p) mod 784
    for (int p = tid; p < 784; p += 256) {
        int s = (11 * p) % 784;
        xs[(s / 28 + 1) * 30 + s % 28 + 1] = x[(size_t)b * IMG + p];
    }
    if (tid < 16) h_bf[(size_t)b * KP + 784 + tid] = __float2bfloat16(0.f);
    __syncthreads();

    const f32x4* Tc = (const f32x4*)T4 + myc * 784;
    // conv0: vertical pairs (r0, c), (r0+1, c); r0 even
    for (int pi = tid; pi < 392; pi += 256) {
        int rp = pi / 28, c = pi % 28;
        int r0 = rp * 2;
        float w[4][3];
#pragma unroll
        for (int i = 0; i < 4; ++i)
#pragma unroll
            for (int j = 0; j < 3; ++j)
                w[i][j] = xs[(r0 + i) * 30 + c + j];
        int pixA = r0 * 28 + c;
        f32x4 A = Tc[pixA];
        f32x4 Bq = Tc[pixA + 28];
        int clA = (9 * r0 + 7 * c + 6) % 11;
        int clB = clA + 9; if (clB >= 11) clB -= 11;
        const f32x4* wrA = (const f32x4*)&wt2[clA * 9];
        const f32x4* wrB = (const f32x4*)&wt2[clB * 9];
#pragma unroll
        for (int dr = 0; dr < 3; ++dr)
#pragma unroll
            for (int dc = 0; dc < 3; ++dc) {
                int tap = dr * 3 + dc;
                float va = w[dr][dc], vb = w[dr + 1][dc];
                f32x4 vva = {va, va, va, va};
                f32x4 vvb = {vb, vb, vb, vb};
                A  = __builtin_elementwise_fma(vva, wrA[tap], A);
                Bq = __builtin_elementwise_fma(vvb, wrB[tap], Bq);
            }
        hs0[(r0 + 1) * 30 + c + 1] =
            make_float4(fmaxf(A.x, 0.f), fmaxf(A.y, 0.f), fmaxf(A.z, 0.f), 0.f);
        hs0[(r0 + 2) * 30 + c + 1] =
            make_float4(fmaxf(Bq.x, 0.f), fmaxf(Bq.y, 0.f), fmaxf(Bq.z, 0.f), 0.f);
    }
    __syncthreads();

    // conv1: vertical pairs, pixel-independent packed weights
    const f32x4* w1v = (const f32x4*)w1p;
    for (int pi = tid; pi < 392; pi += 256) {
        int rp = pi / 28, c = pi % 28;
        int r0 = rp * 2;
        f32x4 A = {0.f, 0.f, 0.f, 0.f};
        f32x4 Bq = {0.f, 0.f, 0.f, 0.f};
#pragma unroll
        for (int dr = 0; dr < 4; ++dr)
#pragma unroll
            for (int dc = 0; dc < 3; ++dc) {
                f32x4 v = *(const f32x4*)&hs0[(r0 + dr) * 30 + c + dc];
                if (dr < 3)
                    A = __builtin_elementwise_fma(v, w1v[dr * 3 + dc], A);
                if (dr > 0)
                    Bq = __builtin_elementwise_fma(v, w1v[(dr - 1) * 3 + dc], Bq);
            }
        float a = A.x + A.y + A.z;
        float bv = Bq.x + Bq.y + Bq.z;
        h_bf[(size_t)b * KP + r0 * 28 + c] = __float2bfloat16(fmaxf(a, 0.f));
        h_bf[(size_t)b * KP + (r0 + 1) * 28 + c] = __float2bfloat16(fmaxf(bv, 0.f));
    }
}

// ---------------------------------------------------------------------------
// K2: fc1 via bf16 MFMA.  h1b[8192,416] = bf16(relu(h @ w^T + b))
// ---------------------------------------------------------------------------
__global__ __launch_bounds__(256) void fc1_mfma(
    const ushort* __restrict__ h_bf,  // [8192,800] bf16
    const ushort* __restrict__ w_bf,  // [400,800] bf16
    const float* __restrict__ bias,   // [400]
    __hip_bfloat16* __restrict__ h1b) // [8192,416] bf16
{
    __shared__ ushort Bs[80][40];   // B tile [n][k], stride 40 (pad)

    const int tid  = threadIdx.x;
    const int wid  = tid >> 6;
    const int lane = tid & 63;
    const int l15  = lane & 15;
    const int lq   = lane >> 4;       // k-quadrant 0..3
    const int bm   = blockIdx.x * 128;
    const int bn   = blockIdx.y * 80;

    f32x4 acc[2][5] = {};

    const int n0 = tid >> 2;          // 0..63  (staging row)
    const int kq0 = tid & 3;          // staging k-quadrant

    for (int k0 = 0; k0 < KP; k0 += 32) {
        bf16x8 s0 = *(const bf16x8*)&w_bf[(size_t)(bn + n0) * KP + k0 + kq0 * 8];
        bf16x8 s1;
        if (tid < 64)
            s1 = *(const bf16x8*)&w_bf[(size_t)(bn + 64 + n0) * KP + k0 + kq0 * 8];
        bf16x8 a0 = *(const bf16x8*)&h_bf[(size_t)(bm + wid * 32 + l15) * KP + k0 + lq * 8];
        bf16x8 a1 = *(const bf16x8*)&h_bf[(size_t)(bm + wid * 32 + 16 + l15) * KP + k0 + lq * 8];
        __syncthreads();
        *(bf16x8*)&Bs[n0][kq0 * 8] = s0;
        if (tid < 64) *(bf16x8*)&Bs[64 + n0][kq0 * 8] = s1;
        __syncthreads();
#pragma unroll
        for (int nf = 0; nf < 5; ++nf) {
            bf16x8 bfr = *(const bf16x8*)&Bs[nf * 16 + l15][lq * 8];
            acc[0][nf] = __builtin_amdgcn_mfma_f32_16x16x32_bf16(a0, bfr, acc[0][nf], 0, 0, 0);
            acc[1][nf] = __builtin_amdgcn_mfma_f32_16x16x32_bf16(a1, bfr, acc[1][nf], 0, 0, 0);
        }
    }

#pragma unroll
    for (int nf = 0; nf < 5; ++nf) {
        int col = bn + nf * 16 + l15;
        float bv = bias[col];
#pragma unroll
        for (int mr = 0; mr < 2; ++mr)
#pragma unroll
            for (int v = 0; v < 4; ++v) {
                int row = bm + wid * 32 + mr * 16 + lq * 4 + v;
                h1b[(size_t)row * KP2 + col] =
                    __float2bfloat16(fmaxf(acc[mr][nf][v] + bv, 0.f));
            }
    }
    if (blockIdx.y == 4) {
#pragma unroll
        for (int mr = 0; mr < 2; ++mr)
#pragma unroll
            for (int v = 0; v < 4; ++v) {
                int row = bm + wid * 32 + mr * 16 + lq * 4 + v;
                h1b[(size_t)row * KP2 + 400 + l15] = __float2bfloat16(0.f);
            }
    }
}

// ---------------------------------------------------------------------------
// K3: FUSED fc2 + fc3 via bf16 MFMA. h3 stored as bf16.
// ---------------------------------------------------------------------------
__global__ __launch_bounds__(256) void fc23_mfma(
    const ushort* __restrict__ h1b,   // [8192,416] bf16
    const ushort* __restrict__ w2bf,  // [48,416] bf16
    const float* __restrict__ b21, const float* __restrict__ b22,
    const int* __restrict__ cls,
    const ushort* __restrict__ w3bf,  // [400,32] bf16
    const float* __restrict__ fc3_b,  // [392]
    float* __restrict__ out,
    __hip_bfloat16* __restrict__ h3b) // [8192,392] bf16
{
    __shared__ ushort zs[128 * 32];

    const int tid  = threadIdx.x;
    const int wid  = tid >> 6;
    const int lane = tid & 63;
    const int l15  = lane & 15;
    const int lq   = lane >> 4;
    const int bm   = blockIdx.x * 128;

    // ---- Phase A: fc2 ----
    f32x4 acc[2][3] = {};
    for (int k0 = 0; k0 < KP2; k0 += 32) {
        bf16x8 a0 = *(const bf16x8*)&h1b[(size_t)(bm + wid * 32 + l15) * KP2 + k0 + lq * 8];
        bf16x8 a1 = *(const bf16x8*)&h1b[(size_t)(bm + wid * 32 + 16 + l15) * KP2 + k0 + lq * 8];
#pragma unroll
        for (int nf = 0; nf < 3; ++nf) {
            bf16x8 bfr = *(const bf16x8*)&w2bf[(size_t)(nf * 16 + l15) * KP2 + k0 + lq * 8];
            acc[0][nf] = __builtin_amdgcn_mfma_f32_16x16x32_bf16(a0, bfr, acc[0][nf], 0, 0, 0);
            acc[1][nf] = __builtin_amdgcn_mfma_f32_16x16x32_bf16(a1, bfr, acc[1][nf], 0, 0, 0);
        }
    }

    const size_t base = (size_t)BATCH * IMG;
#pragma unroll
    for (int nf = 0; nf < 3; ++nf) {
        int col = nf * 16 + l15;
        if (col < 40) {
            bool is_mu = (col < 20);
            int ccol = is_mu ? col : col - 20;
            float bv = is_mu ? b21[ccol] : b22[ccol];
            size_t obase = is_mu ? base : base + (size_t)BATCH * 20;
#pragma unroll
            for (int mr = 0; mr < 2; ++mr)
#pragma unroll
                for (int v = 0; v < 4; ++v) {
                    int rl = wid * 32 + mr * 16 + lq * 4 + v;
                    float val = acc[mr][nf][v] + bv;
                    out[obase + (size_t)(bm + rl) * 20 + ccol] = val;
                    if (is_mu) {
                        __hip_bfloat16 hb = __float2bfloat16(val);
                        zs[rl * 32 + ccol] = *(ushort*)&hb;
                    }
                }
        }
    }
    // one-hot + pad cols 20..31
    for (int i = tid; i < 128 * 12; i += 256) {
        int rl = i / 12, j = i % 12;
        float v = (j < 10 && cls[bm + rl] == j) ? 1.f : 0.f;
        __hip_bfloat16 hb = __float2bfloat16(v);
        zs[rl * 32 + 20 + j] = *(ushort*)&hb;
    }
    __syncthreads();

    // ---- Phase B: fc3 (K=32 single step) ----
    bf16x8 a0 = *(const bf16x8*)&zs[(wid * 32 + l15) * 32 + lq * 8];
    bf16x8 a1 = *(const bf16x8*)&zs[(wid * 32 + 16 + l15) * 32 + lq * 8];

#pragma unroll 1
    for (int bnn = 0; bnn < 5; ++bnn) {
        int bn = bnn * 80;
        f32x4 acc3[2][5] = {};
#pragma unroll
        for (int nf = 0; nf < 5; ++nf) {
            bf16x8 bfr = *(const bf16x8*)&w3bf[(size_t)(bn + nf * 16 + l15) * 32 + lq * 8];
            acc3[0][nf] = __builtin_amdgcn_mfma_f32_16x16x32_bf16(a0, bfr, acc3[0][nf], 0, 0, 0);
            acc3[1][nf] = __builtin_amdgcn_mfma_f32_16x16x32_bf16(a1, bfr, acc3[1][nf], 0, 0, 0);
        }
#pragma unroll
        for (int nf = 0; nf < 5; ++nf) {
            int col = bn + nf * 16 + l15;
            if (col < 392) {
                float bv = fc3_b[col];
#pragma unroll
                for (int mr = 0; mr < 2; ++mr)
#pragma unroll
                    for (int v = 0; v < 4; ++v) {
                        int row = bm + wid * 32 + mr * 16 + lq * 4 + v;
                        h3b[(size_t)row * 392 + col] =
                            __float2bfloat16(fmaxf(acc3[mr][nf][v] + bv, 0.f));
                    }
            }
        }
    }
}

// ---------------------------------------------------------------------------
// K4: decoder — h3(bf16) load + PAIRED deconv0 + wave-parity deconv1 +
// PAIRED deconv2 (+__expf sigmoid).  d0in aliased onto d1s.
// ---------------------------------------------------------------------------
__global__ __launch_bounds__(256, 8) void decoder_kernel(
    const ushort* __restrict__ h3g,   // [8192,392] bf16
    const float* __restrict__ dw0p,   // 216 floats (packed deconv0 weights)
    const float* __restrict__ dw2p,   // [9] float4 packed
    const float* __restrict__ WF4g,   // 576 floats
    float* __restrict__ out)
{
    __shared__ float4 d0sp[3][16 * 16];    // per-cblk planes, plain layout
    __shared__ float4 d1s[30 * 30];        // [30][30]; also hosts d0in early
    float* d0inS = (float*)d1s;

    const int b = blockIdx.x;
    const int tid = threadIdx.x;

    for (int i = tid; i < 2 * 16 * 17; i += 256) d0inS[i] = 0.f;
    for (int i = tid; i < 60; i += 256) {
        int r, c;
        if (i < 16)      { r = 0;  c = i; }
        else if (i < 32) { r = 15; c = i - 16; }
        else if (i < 46) { r = 1 + (i - 32); c = 0; }
        else             { r = 1 + (i - 46); c = 15; }
        int p = r * 16 + c;
        d0sp[0][p] = d0sp[1][p] = d0sp[2][p] = make_float4(0.f, 0.f, 0.f, 0.f);
    }
    __syncthreads();

    // load h3 (bf16, fc3 output, already relu'd): 49 coalesced bf16x8 reads
    if (tid < 49) {
        bf16x8 v = *(const bf16x8*)&h3g[(size_t)b * 392 + tid * 8];
#pragma unroll
        for (int j = 0; j < 8; ++j) {
            int i = tid * 8 + j;
            int ch = i / 196, rem = i % 196;
            ushort u = (ushort)v[j];
            __hip_bfloat16 hb = *(__hip_bfloat16*)&u;
            d0inS[ch * 272 + (rem / 14 + 1) * 17 + (rem % 14 + 1)] =
                __bfloat162float(hb);
        }
    }
    __syncthreads();

    // deconv0: VERTICAL PAIR per thread (98 threads), shared 4x3x2 window
    if (tid < 98) {
        int rp = tid / 14, c = tid % 14;
        int r0 = rp * 2;
        f32x4 A0[3] = {};
        f32x4 A1[3] = {};
        const f32x4* wps = (const f32x4*)dw0p;
#pragma unroll
        for (int i = 0; i < 2; ++i)
#pragma unroll
            for (int dr = 0; dr < 4; ++dr)
#pragma unroll
                for (int dc = 0; dc < 3; ++dc) {
                    float v = d0inS[i * 272 + (r0 + dr) * 17 + (c + dc)];
                    f32x4 vv = {v, v, v, v};
                    if (dr < 3) {
                        int t = (i * 9 + dr * 3 + dc) * 3;
#pragma unroll
                        for (int cb = 0; cb < 3; ++cb)
                            A0[cb] = __builtin_elementwise_fma(vv, wps[t + cb], A0[cb]);
                    }
                    if (dr > 0) {
                        int t = (i * 9 + (dr - 1) * 3 + dc) * 3;
#pragma unroll
                        for (int cb = 0; cb < 3; ++cb)
                            A1[cb] = __builtin_elementwise_fma(vv, wps[t + cb], A1[cb]);
                    }
                }
        int p0 = (r0 + 1) * 16 + (c + 1);
        int p1 = (r0 + 2) * 16 + (c + 1);
        f32x4 zero = {0.f, 0.f, 0.f, 0.f};
#pragma unroll
        for (int cb = 0; cb < 3; ++cb) {
            f32x4 m0 = __builtin_elementwise_max(A0[cb], zero);
            f32x4 m1 = __builtin_elementwise_max(A1[cb], zero);
            d0sp[cb][p0] = *(float4*)&m0;
            d0sp[cb][p1] = *(float4*)&m1;
        }
    }
    __syncthreads();   // d0in reads done -> d1s region free for reuse

    // d1s border zeroing, same phase as deconv1 (disjoint addresses)
    for (int i = tid; i < 116; i += 256) {
        int r, c;
        if (i < 30)      { r = 0;  c = i; }
        else if (i < 60) { r = 29; c = i - 30; }
        else if (i < 88) { r = 1 + (i - 60); c = 0; }
        else             { r = 1 + (i - 88); c = 29; }
        d1s[r * 30 + c] = make_float4(0.f, 0.f, 0.f, 0.f);
    }

    // deconv1: wave w owns parity w. Vertical q-pair per thread; f32x2
    // packed accumulators; weights via wave-uniform global -> SGPRs.
    {
        const int wid  = tid >> 6;          // parity, wave-uniform
        const int lane = tid & 63;
        const int pr = wid >> 1, pc = wid & 1;
        const f32x4* wgs = (const f32x4*)(WF4g +
            __builtin_amdgcn_readfirstlane(wid) * 144);
#pragma unroll 1
        for (int pp = 0; pp < 2; ++pp) {
            int pi = pp * 64 + lane;
            if (pi < 98) {
                int qpr = pi / 14, qc = pi - qpr * 14;
                int qr0 = qpr * 2;
                int base = (qr0 + pr) * 16 + qc + pc;
                f32x2 A0[3] = {{0.f, 0.f}, {0.f, 0.f}, {0.f, 0.f}};
                f32x2 A1[3] = {{0.f, 0.f}, {0.f, 0.f}, {0.f, 0.f}};
#pragma unroll
                for (int cb = 0; cb < 3; ++cb) {
                    f32x4 v0 = *(const f32x4*)&d0sp[cb][base];
                    f32x4 v1 = *(const f32x4*)&d0sp[cb][base + 1];
                    f32x4 v2 = *(const f32x4*)&d0sp[cb][base + 16];
                    f32x4 v3 = *(const f32x4*)&d0sp[cb][base + 17];
                    f32x4 v4 = *(const f32x4*)&d0sp[cb][base + 32];
                    f32x4 v5 = *(const f32x4*)&d0sp[cb][base + 33];
#pragma unroll
                    for (int o = 0; o < 3; ++o) {
                        f32x4 w00 = wgs[(o * 4 + 0) * 3 + cb];
                        f32x4 w01 = wgs[(o * 4 + 1) * 3 + cb];
                        f32x4 w10 = wgs[(o * 4 + 2) * 3 + cb];
                        f32x4 w11 = wgs[(o * 4 + 3) * 3 + cb];
                        A0[o] = __builtin_elementwise_fma(v0.lo, w00.lo, A0[o]);
                        A0[o] = __builtin_elementwise_fma(v0.hi, w00.hi, A0[o]);
                        A0[o] = __builtin_elementwise_fma(v1.lo, w01.lo, A0[o]);
                        A0[o] = __builtin_elementwise_fma(v1.hi, w01.hi, A0[o]);
                        A0[o] = __builtin_elementwise_fma(v2.lo, w10.lo, A0[o]);
                        A0[o] = __builtin_elementwise_fma(v2.hi, w10.hi, A0[o]);
                        A0[o] = __builtin_elementwise_fma(v3.lo, w11.lo, A0[o]);
                        A0[o] = __builtin_elementwise_fma(v3.hi, w11.hi, A0[o]);
                        A1[o] = __builtin_elementwise_fma(v2.lo, w00.lo, A1[o]);
                        A1[o] = __builtin_elementwise_fma(v2.hi, w00.hi, A1[o]);
                        A1[o] = __builtin_elementwise_fma(v3.lo, w01.lo, A1[o]);
                        A1[o] = __builtin_elementwise_fma(v3.hi, w01.hi, A1[o]);
                        A1[o] = __builtin_elementwise_fma(v4.lo, w10.lo, A1[o]);
                        A1[o] = __builtin_elementwise_fma(v4.hi, w10.hi, A1[o]);
                        A1[o] = __builtin_elementwise_fma(v5.lo, w11.lo, A1[o]);
                        A1[o] = __builtin_elementwise_fma(v5.hi, w11.hi, A1[o]);
                    }
                }
                int r0 = 2 * qr0 + pr, c = 2 * qc + pc;
                d1s[(r0 + 1) * 30 + c + 1] =
                    make_float4(fmaxf(A0[0].x + A0[0].y, 0.f),
                                fmaxf(A0[1].x + A0[1].y, 0.f),
                                fmaxf(A0[2].x + A0[2].y, 0.f), 0.f);
                d1s[(r0 + 3) * 30 + c + 1] =
                    make_float4(fmaxf(A1[0].x + A1[0].y, 0.f),
                                fmaxf(A1[1].x + A1[1].y, 0.f),
                                fmaxf(A1[2].x + A1[2].y, 0.f), 0.f);
            }
        }
    }
    __syncthreads();

    // deconv2: VERTICAL PAIR per thread, shared 4x3 window + fast sigmoid
    const f32x4* dw2v = (const f32x4*)dw2p;
    for (int pi = tid; pi < 392; pi += 256) {
        int rp = pi / 28, c = pi % 28;
        int r0 = rp * 2;
        f32x4 A = {0.f, 0.f, 0.f, 0.f};
        f32x4 Bq = {0.f, 0.f, 0.f, 0.f};
#pragma unroll
        for (int dr = 0; dr < 4; ++dr)
#pragma unroll
            for (int dc = 0; dc < 3; ++dc) {
                f32x4 v = *(const f32x4*)&d1s[(r0 + dr) * 30 + c + dc];
                if (dr < 3)
                    A = __builtin_elementwise_fma(v, dw2v[dr * 3 + dc], A);
                if (dr > 0)
                    Bq = __builtin_elementwise_fma(v, dw2v[(dr - 1) * 3 + dc], Bq);
            }
        float a = A.x + A.y + A.z;
        float bv = Bq.x + Bq.y + Bq.z;
        out[(size_t)b * IMG + r0 * 28 + c] = 1.f / (1.f + __expf(-a));
        out[(size_t)b * IMG + (r0 + 1) * 28 + c] = 1.f / (1.f + __expf(-bv));
    }
}

// ---------------------------------------------------------------------------
extern "C" void kernel_launch(void* const* d_in, const int* in_sizes, int n_in,
                              void* d_out, int out_size, void* d_ws, size_t ws_size,
                              hipStream_t stream) {
    const float* x     = (const float*)d_in[0];
    const int*   cls   = (const int*)d_in[1];
    const float* w0    = (const float*)d_in[2];
    const float* w1    = (const float*)d_in[3];
    const float* fc1_w = (const float*)d_in[4];
    const float* fc1_b = (const float*)d_in[5];
    const float* w21   = (const float*)d_in[6];
    const float* b21   = (const float*)d_in[7];
    const float* w22   = (const float*)d_in[8];
    const float* b22   = (const float*)d_in[9];
    const float* fc3_w = (const float*)d_in[10];
    const float* fc3_b = (const float*)d_in[11];
    const float* dw0   = (const float*)d_in[12];
    const float* dw1   = (const float*)d_in[13];
    const float* dw2   = (const float*)d_in[14];

    float* out = (float*)d_out;
    char*  ws  = (char*)d_ws;
    __hip_bfloat16* h_bf = (__hip_bfloat16*)ws;                    // 13,107,200 B
    __hip_bfloat16* h1b  = h_bf + (size_t)BATCH * KP;              //  6,815,744 B
    __hip_bfloat16* h3b  = h1b + (size_t)BATCH * KP2;              //  6,422,528 B
    float* T4   = (float*)(h3b + (size_t)BATCH * 392);             //    125,440 B
    float* WF4  = T4 + 10 * 784 * 4;                               //      2,304 B
    __hip_bfloat16* w_bf  = (__hip_bfloat16*)(WF4 + 576);          //    640,000 B
    __hip_bfloat16* w2bf  = w_bf + 400 * KP;                       //     39,936 B
    __hip_bfloat16* w3bf  = w2bf + 48 * KP2;                       //     25,600 B
    float* w1p  = (float*)(w3bf + 400 * 32);                       //        144 B
    float* dw2p = w1p + 36;                                        //        144 B
    float* dw0p = dw2p + 36;                                       //        864 B

    precompute_kernel<<<60, 256, 0, stream>>>(w0, w1, dw0, dw1, dw2, fc1_w,
                                              w21, w22, fc3_w, T4, WF4, w1p,
                                              dw2p, dw0p, w_bf, w2bf, w3bf);
    encoder_kernel<<<BATCH, 256, 0, stream>>>(x, cls, w0, w1p, T4, h_bf);
    fc1_mfma<<<dim3(64, 5), 256, 0, stream>>>((const ushort*)h_bf,
                                              (const ushort*)w_bf, fc1_b, h1b);
    fc23_mfma<<<64, 256, 0, stream>>>((const ushort*)h1b, (const ushort*)w2bf,
                                      b21, b22, cls, (const ushort*)w3bf,
                                      fc3_b, out, h3b);
    decoder_kernel<<<BATCH, 256, 0, stream>>>((const ushort*)h3b, dw0p, dw2p,
                                              WF4, out);
}

// Round 20
// 127.837 us; speedup vs baseline: 1.0310x; 1.0310x over previous
//
#include <hip/hip_runtime.h>
#include <hip/hip_bf16.h>
#include <math.h>

#define BATCH 8192
#define IMG 784   // 28*28
#define KP 800    // fc1 K padded to multiple of 32
#define KP2 416   // fc2 K padded (400 -> 416)

typedef short  bf16x8 __attribute__((ext_vector_type(8)));
typedef float  f32x4  __attribute__((ext_vector_type(4)));
typedef float  f32x2  __attribute__((ext_vector_type(2)));

// ---------------------------------------------------------------------------
// K0: precompute (a) per-class conv0 one-hot tables T[10][3][784],
// (b) parity-folded deconv1 weights WF4 + packed w1p/dw2p/dw0p,
// (c) fc1_w -> bf16 [400][800], (d) fc2 weights -> bf16 [48][416].
// ---------------------------------------------------------------------------
__global__ __launch_bounds__(256) void precompute_kernel(
    const float* __restrict__ w0,    // [3,11,3,3]
    const float* __restrict__ w1,    // [1,3,3,3]
    const float* __restrict__ dw0,   // [11,2,3,3]
    const float* __restrict__ dw1,   // [3,11,3,3]
    const float* __restrict__ dw2,   // [1,3,3,3]
    const float* __restrict__ fc1w,  // [400,784]
    const float* __restrict__ w21,   // [20,400]
    const float* __restrict__ w22,   // [20,400]
    float* __restrict__ T,           // [10,3,784]
    float* __restrict__ WF4,         // 576 floats
    float* __restrict__ w1p,         // [9]*4 floats
    float* __restrict__ dw2p,        // [9]*4 floats
    float* __restrict__ dw0p,        // [2*9*3]*4 = 216 floats
    __hip_bfloat16* __restrict__ wbf,  // [400,800]
    __hip_bfloat16* __restrict__ w2bf) // [48,416]
{
    const int blk = blockIdx.x, tid = threadIdx.x;
    if (blk < 10) {
        const int t = blk;
        for (int idx = tid; idx < 3 * 784; idx += 256) {
            int o = idx / 784, pix = idx % 784;
            int r = pix / 28, c = pix % 28;
            float acc = 0.f;
#pragma unroll
            for (int dr = 0; dr < 3; ++dr)
#pragma unroll
                for (int dc = 0; dc < 3; ++dc) {
                    int rr = r + dr - 1, cc = c + dc - 1;
                    if (rr < 0 || rr > 27 || cc < 0 || cc > 27) continue;
                    int s = rr * 28 + cc;
                    int i = ((4 * (t + 1 - s)) % 11 + 11) % 11;
                    acc += w0[(o * 11 + i) * 9 + dr * 3 + dc];
                }
            T[(t * 3 + o) * 784 + pix] = acc;
        }
    } else if (blk == 10) {
        // WF4 flat idx = (((par*3+o)*4+uv)*3+cb)*4+j ; channel = 4*cb+j
        for (int idx = tid; idx < 576; idx += 256) {
            int j = idx & 3;
            int rest = idx >> 2;
            int cb = rest % 3;
            int rest2 = rest / 3;
            int uv = rest2 % 4;
            int rest3 = rest2 / 4;
            int o = rest3 % 3;
            int par = rest3 / 3;
            int ch = cb * 4 + j;
            float acc = 0.f;
            if (ch < 11) {
                int u = uv >> 1, v = uv & 1;
                int pr = par >> 1, pc = par & 1;
                for (int dr = 0; dr < 3; ++dr) {
                    bool rin = (pr == 0) ? (u == 0 ? dr == 0 : dr >= 1)
                                         : (u == 0 ? dr <= 1 : dr == 2);
                    if (!rin) continue;
                    for (int dc = 0; dc < 3; ++dc) {
                        bool cin = (pc == 0) ? (v == 0 ? dc == 0 : dc >= 1)
                                             : (v == 0 ? dc <= 1 : dc == 2);
                        if (cin) acc += dw1[(o * 11 + ch) * 9 + dr * 3 + dc];
                    }
                }
            }
            WF4[idx] = acc;
        }
        // per-tap packed conv1 / deconv2 weights: {w[t], w[9+t], w[18+t], 0}
        if (tid < 9) {
            w1p[tid * 4 + 0] = w1[tid];
            w1p[tid * 4 + 1] = w1[9 + tid];
            w1p[tid * 4 + 2] = w1[18 + tid];
            w1p[tid * 4 + 3] = 0.f;
        } else if (tid < 18) {
            int t = tid - 9;
            dw2p[t * 4 + 0] = dw2[t];
            dw2p[t * 4 + 1] = dw2[9 + t];
            dw2p[t * 4 + 2] = dw2[18 + t];
            dw2p[t * 4 + 3] = 0.f;
        }
        // deconv0 weights channel-minor: dw0p[(i*9+tap)*12 + ch]
        if (tid >= 32 && tid < 248) {
            int idx = tid - 32;            // 0..215
            int j  = idx & 3;
            int cb = (idx >> 2) % 3;
            int t2 = (idx >> 2) / 3;       // i*9 + tap, 0..17
            int i  = t2 / 9, tap = t2 % 9;
            int ch = cb * 4 + j;
            dw0p[t2 * 12 + cb * 4 + j] =
                (ch < 11) ? dw0[(ch * 2 + i) * 9 + tap] : 0.f;
        }
    } else if (blk < 51) {
        // fc1_w fp32 [400,784] -> bf16 [400,800] (cols 784..799 zero)
        const int base = (blk - 11) * 8000;
        for (int i = tid; i < 8000; i += 256) {
            int flat = base + i;
            int n = flat / KP, k = flat % KP;
            float v = (k < 784) ? fc1w[n * 784 + k] : 0.f;
            wbf[flat] = __float2bfloat16(v);
        }
    } else {
        // fc2 weights -> bf16 [48,416]: rows 0-19 w21, 20-39 w22, 40-47 zero
        const int base = (blk - 51) * 2496;
        for (int i = tid; i < 2496; i += 256) {
            int flat = base + i;
            int j = flat / KP2, k = flat % KP2;
            float v = 0.f;
            if (k < 400) {
                if (j < 20)      v = w21[j * 400 + k];
                else if (j < 40) v = w22[(j - 20) * 400 + k];
            }
            w2bf[flat] = __float2bfloat16(v);
        }
    }
}

// ---------------------------------------------------------------------------
// K1: encoder — sparse-x conv0 + conv1, both with VERTICAL 2-PIXEL PAIRING
// (shared 4x3 window: 12 reads / 2 pixels; 2 loop iterations not 4).
// writes h as bf16 [B][800]
// ---------------------------------------------------------------------------
__global__ __launch_bounds__(256, 4) void encoder_kernel(
    const float* __restrict__ x, const int* __restrict__ cls,
    const float* __restrict__ w0,    // [3,11,3,3]
    const float* __restrict__ w1p,   // [9] float4 packed
    const float* __restrict__ T,     // [10,3,784]
    __hip_bfloat16* __restrict__ h_bf)  // [B,800]
{
    __shared__ float  xs[30 * 30];      // scattered x image, zero border
    __shared__ float4 hs0[30 * 30];     // conv0 out (3ch + pad), zero border
    __shared__ float4 wt2[99];          // [cls 0..10][tap 0..8] pre-permuted

    const int b = blockIdx.x, tid = threadIdx.x;
    const int myc = cls[b];

    for (int i = tid; i < 116; i += 256) {
        int r, c;
        if (i < 30)      { r = 0;  c = i; }
        else if (i < 60) { r = 29; c = i - 30; }
        else if (i < 88) { r = 1 + (i - 60); c = 0; }
        else             { r = 1 + (i - 88); c = 29; }
        xs[r * 30 + c] = 0.f;
        hs0[r * 30 + c] = make_float4(0.f, 0.f, 0.f, 0.f);
    }
    // wt2[cls*9+tap] = w0[:, (cls + kk(tap)) % 11, tap]
    for (int i = tid; i < 99; i += 256) {
        int cl = i / 9, tap = i % 9;
        int kk = (9 * (tap / 3) + 7 * (tap % 3)) % 11;
        int ch = cl + kk;
        if (ch >= 11) ch -= 11;
        wt2[i] = make_float4(w0[ch * 9 + tap], w0[(11 + ch) * 9 + tap],
                             w0[(22 + ch) * 9 + tap], 0.f);
    }
    for (int s = tid; s < 784; s += 256) {
        int ch = (7 * s) % 11;
        int p = (ch * 784 + s) / 11;
        xs[(s / 28 + 1) * 30 + s % 28 + 1] = x[(size_t)b * IMG + p];
    }
    if (tid < 16) h_bf[(size_t)b * KP + 784 + tid] = __float2bfloat16(0.f);
    __syncthreads();

    const float* Tc = T + myc * 2352;
    // conv0: vertical pairs (r0, c), (r0+1, c); r0 even
    for (int pi = tid; pi < 392; pi += 256) {
        int rp = pi / 28, c = pi % 28;
        int r0 = rp * 2;
        float w[4][3];
#pragma unroll
        for (int i = 0; i < 4; ++i)
#pragma unroll
            for (int j = 0; j < 3; ++j)
                w[i][j] = xs[(r0 + i) * 30 + c + j];
        int pixA = r0 * 28 + c;
        f32x4 A = {Tc[pixA], Tc[784 + pixA], Tc[1568 + pixA], 0.f};
        f32x4 Bq = {Tc[pixA + 28], Tc[812 + pixA], Tc[1596 + pixA], 0.f};
        int clA = (9 * r0 + 7 * c + 6) % 11;
        int clB = clA + 9; if (clB >= 11) clB -= 11;
        const f32x4* wrA = (const f32x4*)&wt2[clA * 9];
        const f32x4* wrB = (const f32x4*)&wt2[clB * 9];
#pragma unroll
        for (int dr = 0; dr < 3; ++dr)
#pragma unroll
            for (int dc = 0; dc < 3; ++dc) {
                int tap = dr * 3 + dc;
                float va = w[dr][dc], vb = w[dr + 1][dc];
                f32x4 vva = {va, va, va, va};
                f32x4 vvb = {vb, vb, vb, vb};
                A  = __builtin_elementwise_fma(vva, wrA[tap], A);
                Bq = __builtin_elementwise_fma(vvb, wrB[tap], Bq);
            }
        hs0[(r0 + 1) * 30 + c + 1] =
            make_float4(fmaxf(A.x, 0.f), fmaxf(A.y, 0.f), fmaxf(A.z, 0.f), 0.f);
        hs0[(r0 + 2) * 30 + c + 1] =
            make_float4(fmaxf(Bq.x, 0.f), fmaxf(Bq.y, 0.f), fmaxf(Bq.z, 0.f), 0.f);
    }
    __syncthreads();

    // conv1: vertical pairs, pixel-independent packed weights
    const f32x4* w1v = (const f32x4*)w1p;
    for (int pi = tid; pi < 392; pi += 256) {
        int rp = pi / 28, c = pi % 28;
        int r0 = rp * 2;
        f32x4 A = {0.f, 0.f, 0.f, 0.f};
        f32x4 Bq = {0.f, 0.f, 0.f, 0.f};
#pragma unroll
        for (int dr = 0; dr < 4; ++dr)
#pragma unroll
            for (int dc = 0; dc < 3; ++dc) {
                f32x4 v = *(const f32x4*)&hs0[(r0 + dr) * 30 + c + dc];
                if (dr < 3)
                    A = __builtin_elementwise_fma(v, w1v[dr * 3 + dc], A);
                if (dr > 0)
                    Bq = __builtin_elementwise_fma(v, w1v[(dr - 1) * 3 + dc], Bq);
            }
        float a = A.x + A.y + A.z;
        float bv = Bq.x + Bq.y + Bq.z;
        h_bf[(size_t)b * KP + r0 * 28 + c] = __float2bfloat16(fmaxf(a, 0.f));
        h_bf[(size_t)b * KP + (r0 + 1) * 28 + c] = __float2bfloat16(fmaxf(bv, 0.f));
    }
}

// ---------------------------------------------------------------------------
// K2: fc1 via bf16 MFMA.  h1b[8192,416] = bf16(relu(h @ w^T + b))
// ---------------------------------------------------------------------------
__global__ __launch_bounds__(256) void fc1_mfma(
    const ushort* __restrict__ h_bf,  // [8192,800] bf16
    const ushort* __restrict__ w_bf,  // [400,800] bf16
    const float* __restrict__ bias,   // [400]
    __hip_bfloat16* __restrict__ h1b) // [8192,416] bf16
{
    __shared__ ushort Bs[80][40];   // B tile [n][k], stride 40 (pad)

    const int tid  = threadIdx.x;
    const int wid  = tid >> 6;
    const int lane = tid & 63;
    const int l15  = lane & 15;
    const int lq   = lane >> 4;       // k-quadrant 0..3
    const int bm   = blockIdx.x * 128;
    const int bn   = blockIdx.y * 80;

    f32x4 acc[2][5] = {};

    const int n0 = tid >> 2;          // 0..63  (staging row)
    const int kq0 = tid & 3;          // staging k-quadrant

    for (int k0 = 0; k0 < KP; k0 += 32) {
        bf16x8 s0 = *(const bf16x8*)&w_bf[(size_t)(bn + n0) * KP + k0 + kq0 * 8];
        bf16x8 s1;
        if (tid < 64)
            s1 = *(const bf16x8*)&w_bf[(size_t)(bn + 64 + n0) * KP + k0 + kq0 * 8];
        bf16x8 a0 = *(const bf16x8*)&h_bf[(size_t)(bm + wid * 32 + l15) * KP + k0 + lq * 8];
        bf16x8 a1 = *(const bf16x8*)&h_bf[(size_t)(bm + wid * 32 + 16 + l15) * KP + k0 + lq * 8];
        __syncthreads();
        *(bf16x8*)&Bs[n0][kq0 * 8] = s0;
        if (tid < 64) *(bf16x8*)&Bs[64 + n0][kq0 * 8] = s1;
        __syncthreads();
#pragma unroll
        for (int nf = 0; nf < 5; ++nf) {
            bf16x8 bfr = *(const bf16x8*)&Bs[nf * 16 + l15][lq * 8];
            acc[0][nf] = __builtin_amdgcn_mfma_f32_16x16x32_bf16(a0, bfr, acc[0][nf], 0, 0, 0);
            acc[1][nf] = __builtin_amdgcn_mfma_f32_16x16x32_bf16(a1, bfr, acc[1][nf], 0, 0, 0);
        }
    }

#pragma unroll
    for (int nf = 0; nf < 5; ++nf) {
        int col = bn + nf * 16 + l15;
        float bv = bias[col];
#pragma unroll
        for (int mr = 0; mr < 2; ++mr)
#pragma unroll
            for (int v = 0; v < 4; ++v) {
                int row = bm + wid * 32 + mr * 16 + lq * 4 + v;
                h1b[(size_t)row * KP2 + col] =
                    __float2bfloat16(fmaxf(acc[mr][nf][v] + bv, 0.f));
            }
    }
    if (blockIdx.y == 4) {
#pragma unroll
        for (int mr = 0; mr < 2; ++mr)
#pragma unroll
            for (int v = 0; v < 4; ++v) {
                int row = bm + wid * 32 + mr * 16 + lq * 4 + v;
                h1b[(size_t)row * KP2 + 400 + l15] = __float2bfloat16(0.f);
            }
    }
}

// ---------------------------------------------------------------------------
// K3: fc21 + fc22 via bf16 MFMA, no LDS.
// ---------------------------------------------------------------------------
__global__ __launch_bounds__(256) void fc2_mfma(
    const ushort* __restrict__ h1b,   // [8192,416] bf16
    const ushort* __restrict__ w2bf,  // [48,416] bf16
    const float* __restrict__ b21, const float* __restrict__ b22,
    float* __restrict__ out)
{
    const int tid  = threadIdx.x;
    const int wid  = tid >> 6;
    const int lane = tid & 63;
    const int l15  = lane & 15;
    const int lq   = lane >> 4;
    const int bm   = blockIdx.x * 128;

    f32x4 acc[2][3] = {};

    for (int k0 = 0; k0 < KP2; k0 += 32) {
        bf16x8 a0 = *(const bf16x8*)&h1b[(size_t)(bm + wid * 32 + l15) * KP2 + k0 + lq * 8];
        bf16x8 a1 = *(const bf16x8*)&h1b[(size_t)(bm + wid * 32 + 16 + l15) * KP2 + k0 + lq * 8];
#pragma unroll
        for (int nf = 0; nf < 3; ++nf) {
            bf16x8 bfr = *(const bf16x8*)&w2bf[(size_t)(nf * 16 + l15) * KP2 + k0 + lq * 8];
            acc[0][nf] = __builtin_amdgcn_mfma_f32_16x16x32_bf16(a0, bfr, acc[0][nf], 0, 0, 0);
            acc[1][nf] = __builtin_amdgcn_mfma_f32_16x16x32_bf16(a1, bfr, acc[1][nf], 0, 0, 0);
        }
    }

    const size_t base = (size_t)BATCH * IMG;
#pragma unroll
    for (int nf = 0; nf < 3; ++nf) {
        int col = nf * 16 + l15;
        if (col < 40) {
            bool is_mu = (col < 20);
            int ccol = is_mu ? col : col - 20;
            float bv = is_mu ? b21[ccol] : b22[ccol];
            size_t obase = is_mu ? base : base + (size_t)BATCH * 20;
#pragma unroll
            for (int mr = 0; mr < 2; ++mr)
#pragma unroll
                for (int v = 0; v < 4; ++v) {
                    int row = bm + wid * 32 + mr * 16 + lq * 4 + v;
                    out[obase + (size_t)row * 20 + ccol] = acc[mr][nf][v] + bv;
                }
        }
    }
}

// ---------------------------------------------------------------------------
// K4: decoder — fc3 + PAIRED deconv0 + wave-parity deconv1 (plain d0sp
// layout) + PAIRED deconv2 (+__expf sigmoid).  d0in aliased onto d1s.
// ---------------------------------------------------------------------------
__global__ __launch_bounds__(256, 8) void decoder_kernel(
    const int* __restrict__ cls,
    const float* __restrict__ fc3_w,  // [392,30]
    const float* __restrict__ fc3_b,  // [392]
    const float* __restrict__ dw0p,   // 216 floats (packed deconv0 weights)
    const float* __restrict__ dw2p,   // [9] float4 packed
    const float* __restrict__ WF4g,   // 576 floats
    float* __restrict__ out)
{
    __shared__ float  z[32];
    __shared__ float4 d0sp[3][16 * 16];    // per-cblk planes, plain layout
    __shared__ float4 d1s[30 * 30];        // [30][30]; also hosts d0in early
    float* d0inS = (float*)d1s;

    const int b = blockIdx.x;
    const int tid = threadIdx.x;
    const int myc = cls[b];
    const float* mu = out + (size_t)BATCH * IMG + (size_t)b * 20;

    for (int i = tid; i < 2 * 16 * 17; i += 256) d0inS[i] = 0.f;
    for (int i = tid; i < 60; i += 256) {
        int r, c;
        if (i < 16)      { r = 0;  c = i; }
        else if (i < 32) { r = 15; c = i - 16; }
        else if (i < 46) { r = 1 + (i - 32); c = 0; }
        else             { r = 1 + (i - 46); c = 15; }
        int p = r * 16 + c;
        d0sp[0][p] = d0sp[1][p] = d0sp[2][p] = make_float4(0.f, 0.f, 0.f, 0.f);
    }
    if (tid < 20) z[tid] = mu[tid];
    else if (tid < 30) z[tid] = (tid - 20 == myc) ? 1.f : 0.f;
    __syncthreads();

    // fc3: [30] -> [392] + relu -> d0in [2][16][17] padded
    for (int j = tid; j < 392; j += 256) {
        float acc = fc3_b[j];
        const float2* wrow = (const float2*)&fc3_w[j * 30];
#pragma unroll
        for (int k = 0; k < 15; ++k) {
            float2 wv = wrow[k];
            acc += z[2 * k] * wv.x + z[2 * k + 1] * wv.y;
        }
        int ch = j / 196, rem = j % 196;
        d0inS[ch * 272 + (rem / 14 + 1) * 17 + (rem % 14 + 1)] = fmaxf(acc, 0.f);
    }
    __syncthreads();

    // deconv0: VERTICAL PAIR per thread (98 threads), shared 4x3x2 window:
    // 24 LDS reads / 2 positions (vs 36). weights wave-uniform -> s_loads.
    if (tid < 98) {
        int rp = tid / 14, c = tid % 14;
        int r0 = rp * 2;
        f32x4 A0[3] = {};
        f32x4 A1[3] = {};
        const f32x4* wps = (const f32x4*)dw0p;
#pragma unroll
        for (int i = 0; i < 2; ++i)
#pragma unroll
            for (int dr = 0; dr < 4; ++dr)
#pragma unroll
                for (int dc = 0; dc < 3; ++dc) {
                    float v = d0inS[i * 272 + (r0 + dr) * 17 + (c + dc)];
                    f32x4 vv = {v, v, v, v};
                    if (dr < 3) {
                        int t = (i * 9 + dr * 3 + dc) * 3;
#pragma unroll
                        for (int cb = 0; cb < 3; ++cb)
                            A0[cb] = __builtin_elementwise_fma(vv, wps[t + cb], A0[cb]);
                    }
                    if (dr > 0) {
                        int t = (i * 9 + (dr - 1) * 3 + dc) * 3;
#pragma unroll
                        for (int cb = 0; cb < 3; ++cb)
                            A1[cb] = __builtin_elementwise_fma(vv, wps[t + cb], A1[cb]);
                    }
                }
        int p0 = (r0 + 1) * 16 + (c + 1);
        int p1 = (r0 + 2) * 16 + (c + 1);
        f32x4 zero = {0.f, 0.f, 0.f, 0.f};
#pragma unroll
        for (int cb = 0; cb < 3; ++cb) {
            f32x4 m0 = __builtin_elementwise_max(A0[cb], zero);
            f32x4 m1 = __builtin_elementwise_max(A1[cb], zero);
            d0sp[cb][p0] = *(float4*)&m0;
            d0sp[cb][p1] = *(float4*)&m1;
        }
    }
    __syncthreads();   // d0in reads done -> d1s region free for reuse

    // d1s border zeroing, same phase as deconv1 (disjoint addresses)
    for (int i = tid; i < 116; i += 256) {
        int r, c;
        if (i < 30)      { r = 0;  c = i; }
        else if (i < 60) { r = 29; c = i - 30; }
        else if (i < 88) { r = 1 + (i - 60); c = 0; }
        else             { r = 1 + (i - 88); c = 29; }
        d1s[r * 30 + c] = make_float4(0.f, 0.f, 0.f, 0.f);
    }

    // deconv1: wave w owns parity w. Vertical q-pair per thread; f32x2
    // packed accumulators; weights via wave-uniform global -> SGPRs.
    {
        const int wid  = tid >> 6;          // parity, wave-uniform
        const int lane = tid & 63;
        const int pr = wid >> 1, pc = wid & 1;
        const f32x4* wgs = (const f32x4*)(WF4g +
            __builtin_amdgcn_readfirstlane(wid) * 144);
#pragma unroll 1
        for (int pp = 0; pp < 2; ++pp) {
            int pi = pp * 64 + lane;
            if (pi < 98) {
                int qpr = pi / 14, qc = pi - qpr * 14;
                int qr0 = qpr * 2;
                int base = (qr0 + pr) * 16 + qc + pc;
                f32x2 A0[3] = {{0.f, 0.f}, {0.f, 0.f}, {0.f, 0.f}};
                f32x2 A1[3] = {{0.f, 0.f}, {0.f, 0.f}, {0.f, 0.f}};
#pragma unroll
                for (int cb = 0; cb < 3; ++cb) {
                    f32x4 v0 = *(const f32x4*)&d0sp[cb][base];
                    f32x4 v1 = *(const f32x4*)&d0sp[cb][base + 1];
                    f32x4 v2 = *(const f32x4*)&d0sp[cb][base + 16];
                    f32x4 v3 = *(const f32x4*)&d0sp[cb][base + 17];
                    f32x4 v4 = *(const f32x4*)&d0sp[cb][base + 32];
                    f32x4 v5 = *(const f32x4*)&d0sp[cb][base + 33];
#pragma unroll
                    for (int o = 0; o < 3; ++o) {
                        f32x4 w00 = wgs[(o * 4 + 0) * 3 + cb];
                        f32x4 w01 = wgs[(o * 4 + 1) * 3 + cb];
                        f32x4 w10 = wgs[(o * 4 + 2) * 3 + cb];
                        f32x4 w11 = wgs[(o * 4 + 3) * 3 + cb];
                        A0[o] = __builtin_elementwise_fma(v0.lo, w00.lo, A0[o]);
                        A0[o] = __builtin_elementwise_fma(v0.hi, w00.hi, A0[o]);
                        A0[o] = __builtin_elementwise_fma(v1.lo, w01.lo, A0[o]);
                        A0[o] = __builtin_elementwise_fma(v1.hi, w01.hi, A0[o]);
                        A0[o] = __builtin_elementwise_fma(v2.lo, w10.lo, A0[o]);
                        A0[o] = __builtin_elementwise_fma(v2.hi, w10.hi, A0[o]);
                        A0[o] = __builtin_elementwise_fma(v3.lo, w11.lo, A0[o]);
                        A0[o] = __builtin_elementwise_fma(v3.hi, w11.hi, A0[o]);
                        A1[o] = __builtin_elementwise_fma(v2.lo, w00.lo, A1[o]);
                        A1[o] = __builtin_elementwise_fma(v2.hi, w00.hi, A1[o]);
                        A1[o] = __builtin_elementwise_fma(v3.lo, w01.lo, A1[o]);
                        A1[o] = __builtin_elementwise_fma(v3.hi, w01.hi, A1[o]);
                        A1[o] = __builtin_elementwise_fma(v4.lo, w10.lo, A1[o]);
                        A1[o] = __builtin_elementwise_fma(v4.hi, w10.hi, A1[o]);
                        A1[o] = __builtin_elementwise_fma(v5.lo, w11.lo, A1[o]);
                        A1[o] = __builtin_elementwise_fma(v5.hi, w11.hi, A1[o]);
                    }
                }
                int r0 = 2 * qr0 + pr, c = 2 * qc + pc;
                d1s[(r0 + 1) * 30 + c + 1] =
                    make_float4(fmaxf(A0[0].x + A0[0].y, 0.f),
                                fmaxf(A0[1].x + A0[1].y, 0.f),
                                fmaxf(A0[2].x + A0[2].y, 0.f), 0.f);
                d1s[(r0 + 3) * 30 + c + 1] =
                    make_float4(fmaxf(A1[0].x + A1[0].y, 0.f),
                                fmaxf(A1[1].x + A1[1].y, 0.f),
                                fmaxf(A1[2].x + A1[2].y, 0.f), 0.f);
            }
        }
    }
    __syncthreads();

    // deconv2: VERTICAL PAIR per thread (392 pairs), shared 4x3 window
    // (12 b128 reads / 2 pixels vs 18) + fast sigmoid
    const f32x4* dw2v = (const f32x4*)dw2p;
    for (int pi = tid; pi < 392; pi += 256) {
        int rp = pi / 28, c = pi % 28;
        int r0 = rp * 2;
        f32x4 A = {0.f, 0.f, 0.f, 0.f};
        f32x4 Bq = {0.f, 0.f, 0.f, 0.f};
#pragma unroll
        for (int dr = 0; dr < 4; ++dr)
#pragma unroll
            for (int dc = 0; dc < 3; ++dc) {
                f32x4 v = *(const f32x4*)&d1s[(r0 + dr) * 30 + c + dc];
                if (dr < 3)
                    A = __builtin_elementwise_fma(v, dw2v[dr * 3 + dc], A);
                if (dr > 0)
                    Bq = __builtin_elementwise_fma(v, dw2v[(dr - 1) * 3 + dc], Bq);
            }
        float a = A.x + A.y + A.z;
        float bv = Bq.x + Bq.y + Bq.z;
        out[(size_t)b * IMG + r0 * 28 + c] = 1.f / (1.f + __expf(-a));
        out[(size_t)b * IMG + (r0 + 1) * 28 + c] = 1.f / (1.f + __expf(-bv));
    }
}

// ---------------------------------------------------------------------------
extern "C" void kernel_launch(void* const* d_in, const int* in_sizes, int n_in,
                              void* d_out, int out_size, void* d_ws, size_t ws_size,
                              hipStream_t stream) {
    const float* x     = (const float*)d_in[0];
    const int*   cls   = (const int*)d_in[1];
    const float* w0    = (const float*)d_in[2];
    const float* w1    = (const float*)d_in[3];
    const float* fc1_w = (const float*)d_in[4];
    const float* fc1_b = (const float*)d_in[5];
    const float* w21   = (const float*)d_in[6];
    const float* b21   = (const float*)d_in[7];
    const float* w22   = (const float*)d_in[8];
    const float* b22   = (const float*)d_in[9];
    const float* fc3_w = (const float*)d_in[10];
    const float* fc3_b = (const float*)d_in[11];
    const float* dw0   = (const float*)d_in[12];
    const float* dw1   = (const float*)d_in[13];
    const float* dw2   = (const float*)d_in[14];

    float* out = (float*)d_out;
    char*  ws  = (char*)d_ws;
    __hip_bfloat16* h_bf = (__hip_bfloat16*)ws;                       // 8192*800 bf16
    __hip_bfloat16* h1b  = (__hip_bfloat16*)(ws + (size_t)BATCH * KP * 2);  // 8192*416 bf16
    float* T    = (float*)(ws + (size_t)BATCH * KP * 2 + (size_t)BATCH * KP2 * 2);
    float* WF4  = T + 10 * 3 * 784;
    __hip_bfloat16* w_bf  = (__hip_bfloat16*)(WF4 + 576);             // 400*800
    __hip_bfloat16* w2bf  = w_bf + 400 * KP;                          // 48*416
    float* w1p  = (float*)(w2bf + 48 * KP2);                          // 36 floats
    float* dw2p = w1p + 36;                                           // 36 floats
    float* dw0p = dw2p + 36;                                          // 216 floats

    precompute_kernel<<<59, 256, 0, stream>>>(w0, w1, dw0, dw1, dw2, fc1_w,
                                              w21, w22, T, WF4, w1p, dw2p,
                                              dw0p, w_bf, w2bf);
    encoder_kernel<<<BATCH, 256, 0, stream>>>(x, cls, w0, w1p, T, h_bf);
    fc1_mfma<<<dim3(64, 5), 256, 0, stream>>>((const ushort*)h_bf,
                                              (const ushort*)w_bf, fc1_b, h1b);
    fc2_mfma<<<64, 256, 0, stream>>>((const ushort*)h1b, (const ushort*)w2bf,
                                     b21, b22, out);
    decoder_kernel<<<BATCH, 256, 0, stream>>>(cls, fc3_w, fc3_b, dw0p, dw2p,
                                              WF4, out);
}